// Round 23
// baseline (85.558 us; speedup 1.0000x reference)
//
#include <hip/hip_runtime.h>

constexpr int NN = 100000;
constexpr int CH = 128;
constexpr int NE = 625000;
constexpr int GEMM_BLOCKS = (NN + 255) / 256;      // 391 (256 rows/block: 8 waves x 16 rows x 2 tiles)
constexpr int BUCKET_BLOCKS = 256;
constexpr int EDGES_PER_BLOCK = (NE + BUCKET_BLOCKS - 1) / BUCKET_BLOCKS;  // 2442
constexpr int NB = 196;                            // ceil(NN/512) coarse buckets
constexpr int CAP = 4096;                          // slots/bucket (max ~3390)
constexpr int WCONV_BLOCKS = 16;

typedef __bf16 bf16x8 __attribute__((ext_vector_type(8)));
typedef __bf16 bf16x4 __attribute__((ext_vector_type(4)));
typedef float  f32x4  __attribute__((ext_vector_type(4)));

__device__ __forceinline__ float bflo(uint u) { return __uint_as_float(u << 16); }
__device__ __forceinline__ float bfhi(uint u) { return __uint_as_float(u & 0xffff0000u); }

__device__ __forceinline__ void async_copy16(const void* g, void* l) {
    __builtin_amdgcn_global_load_lds(
        (const __attribute__((address_space(1))) unsigned int*)(uintptr_t)g,
        (__attribute__((address_space(3))) unsigned int*)(uintptr_t)l,
        16, 0, 0);
}

// ---- prep: init bucket cursors + convert W to bf16 swizzled ----
__global__ __launch_bounds__(256) void prep_kernel(
    int* __restrict__ gcursor, const float* __restrict__ W, __bf16* __restrict__ Wb)
{
    if (blockIdx.x == 0) {
        gcursor[threadIdx.x] = threadIdx.x * CAP;
        return;
    }
    int i = (blockIdx.x - 1) * 256 + threadIdx.x;
    int ch = i >> 5;
    int k0 = (i & 31) * 4;
    float4 v = reinterpret_cast<const float4*>(W)[i];
    bf16x4 h = {(__bf16)v.x, (__bf16)v.y, (__bf16)v.z, (__bf16)v.w};
    *reinterpret_cast<bf16x4*>(&Wb[ch * 128 + (k0 ^ ((ch & 7) << 3))]) = h;
}

// ---- fused: coarse bucketing (blocks < BUCKET_BLOCKS) + MFMA GEMM ----
// GEMM: 2 row-tiles per wave, software-pipelined — tile2's x-loads are
// issued BEFORE tile1's MFMA burst, so their latency hides under compute.
// Bucket: per-edge atomics LDS-only; <=50K global range reservations.
__global__ __launch_bounds__(512) void gemm_bucket_kernel(
    const float* __restrict__ x, const __bf16* __restrict__ Wb,
    const float* __restrict__ b, __bf16* __restrict__ xt,
    const int* __restrict__ ei, int* __restrict__ gcursor, int2* __restrict__ pairs)
{
    __shared__ __bf16 wlds[128 * 128];     // 32 KB; bucket blocks alias it
    const int tid = threadIdx.x;

    if (blockIdx.x < BUCKET_BLOCKS) {
        int* lhist = (int*)wlds;           // [256]
        int* lbase = lhist + 256;          // [256]
        const int e0 = blockIdx.x * EDGES_PER_BLOCK;
        const int myN = min(NE - e0, EDGES_PER_BLOCK);
        if (tid < 256) lhist[tid] = 0;
        __syncthreads();
        for (int i = tid; i < myN; i += 512) {
            int dst = ei[NE + e0 + i];
            atomicAdd(&lhist[dst >> 9], 1);
        }
        __syncthreads();
        if (tid < 256) {
            int c = lhist[tid];
            if (c) lbase[tid] = atomicAdd(&gcursor[tid], c);
            lhist[tid] = 0;
        }
        __syncthreads();
        for (int i = tid; i < myN; i += 512) {
            int src = ei[e0 + i];
            int dst = ei[NE + e0 + i];
            int bin = dst >> 9;
            int r = atomicAdd(&lhist[bin], 1);
            pairs[lbase[bin] + r] = make_int2(src, dst);
        }
        return;
    }

    const int lane = tid & 63;
    const int w    = tid >> 6;             // wave id 0..7
    const int lm = lane & 15;
    const int lk = lane >> 4;
    const int row1 = (blockIdx.x - BUCKET_BLOCKS) * 256 + w * 16 + lm;
    const int row2 = row1 + 128;
    const int rc1  = row1 < NN ? row1 : NN - 1;
    const int rc2  = row2 < NN ? row2 : NN - 1;

    // Tile-1 x loads first (longest latency): 8 independent dwordx4.
    const float* xrow1 = x + (size_t)rc1 * CH;
    float4 xr[8];
    #pragma unroll
    for (int ks = 0; ks < 4; ++ks) {
        const float4* p = reinterpret_cast<const float4*>(xrow1 + ks * 32 + lk * 8);
        xr[ks * 2]     = p[0];
        xr[ks * 2 + 1] = p[1];
    }

    // Async W staging: 2048 granules of 16B over 512 threads = 4 issues.
    const bf16x8* Wb8 = reinterpret_cast<const bf16x8*>(Wb);
    #pragma unroll
    for (int it = 0; it < 4; ++it)
        async_copy16(Wb8 + it * 512 + tid,
                     (char*)wlds + (size_t)(it * 512 + w * 64) * 16);

    // Bias preload (overlaps x/W latency).
    const float4* B4 = reinterpret_cast<const float4*>(b);
    float4 bv[8];
    #pragma unroll
    for (int t = 0; t < 8; ++t) bv[t] = B4[t * 4 + lk];

    // Convert tile-1 x while DMAs fly.
    bf16x8 bfrag1[4];
    #pragma unroll
    for (int ks = 0; ks < 4; ++ks) {
        float4 u = xr[ks * 2], v = xr[ks * 2 + 1];
        bfrag1[ks][0] = (__bf16)u.x; bfrag1[ks][1] = (__bf16)u.y;
        bfrag1[ks][2] = (__bf16)u.z; bfrag1[ks][3] = (__bf16)u.w;
        bfrag1[ks][4] = (__bf16)v.x; bfrag1[ks][5] = (__bf16)v.y;
        bfrag1[ks][6] = (__bf16)v.z; bfrag1[ks][7] = (__bf16)v.w;
    }

    __syncthreads();   // drains vmcnt (x1 loads + LDS DMAs)

    // Issue tile-2 x loads NOW — latency hides under tile-1 MFMA burst.
    const float* xrow2 = x + (size_t)rc2 * CH;
    float4 xr2[8];
    #pragma unroll
    for (int ks = 0; ks < 4; ++ks) {
        const float4* p = reinterpret_cast<const float4*>(xrow2 + ks * 32 + lk * 8);
        xr2[ks * 2]     = p[0];
        xr2[ks * 2 + 1] = p[1];
    }

    const int swz = (lm & 7) << 3;

    // Tile 1: MFMA + store (tile-2 loads in flight).
    #pragma unroll
    for (int t = 0; t < 8; ++t) {
        const int ch = t * 16 + lm;
        f32x4 acc = {bv[t].x, bv[t].y, bv[t].z, bv[t].w};
        #pragma unroll
        for (int ks = 0; ks < 4; ++ks) {
            bf16x8 afrag = *reinterpret_cast<const bf16x8*>(
                &wlds[ch * 128 + ((ks * 32 + lk * 8) ^ swz)]);
            acc = __builtin_amdgcn_mfma_f32_16x16x32_bf16(afrag, bfrag1[ks], acc, 0, 0, 0);
        }
        if (row1 < NN) {
            const int c0 = t * 16 + lk * 4;
            bf16x4 hv = {(__bf16)acc[0], (__bf16)acc[1], (__bf16)acc[2], (__bf16)acc[3]};
            *reinterpret_cast<bf16x4*>(&xt[(size_t)row1 * CH + c0]) = hv;
        }
    }

    // Tile 2: convert (drains x2 — mostly complete) + MFMA + store.
    bf16x8 bfrag2[4];
    #pragma unroll
    for (int ks = 0; ks < 4; ++ks) {
        float4 u = xr2[ks * 2], v = xr2[ks * 2 + 1];
        bfrag2[ks][0] = (__bf16)u.x; bfrag2[ks][1] = (__bf16)u.y;
        bfrag2[ks][2] = (__bf16)u.z; bfrag2[ks][3] = (__bf16)u.w;
        bfrag2[ks][4] = (__bf16)v.x; bfrag2[ks][5] = (__bf16)v.y;
        bfrag2[ks][6] = (__bf16)v.z; bfrag2[ks][7] = (__bf16)v.w;
    }

    #pragma unroll
    for (int t = 0; t < 8; ++t) {
        const int ch = t * 16 + lm;
        f32x4 acc = {bv[t].x, bv[t].y, bv[t].z, bv[t].w};
        #pragma unroll
        for (int ks = 0; ks < 4; ++ks) {
            bf16x8 afrag = *reinterpret_cast<const bf16x8*>(
                &wlds[ch * 128 + ((ks * 32 + lk * 8) ^ swz)]);
            acc = __builtin_amdgcn_mfma_f32_16x16x32_bf16(afrag, bfrag2[ks], acc, 0, 0, 0);
        }
        if (row2 < NN) {
            const int c0 = t * 16 + lk * 4;
            bf16x4 hv = {(__bf16)acc[0], (__bf16)acc[1], (__bf16)acc[2], (__bf16)acc[3]};
            *reinterpret_cast<bf16x4*>(&xt[(size_t)row2 * CH + c0]) = hv;
        }
    }
}

// ---- phase 2: per-bucket LDS counting sort -> dense srcs + offs ----
__global__ __launch_bounds__(256) void place2_kernel(
    const int* __restrict__ gcursor, const int2* __restrict__ pairs,
    int* __restrict__ srcs, int* __restrict__ offs)
{
    __shared__ int cntb[256];
    __shared__ int cnt512[512];
    __shared__ int pref[512];
    __shared__ int dense_base;
    const int tid = threadIdx.x;
    const int bkt = blockIdx.x;

    int c = gcursor[tid] - tid * CAP;     // 0 for unused bins
    cntb[tid] = c;
    __syncthreads();
    for (int off = 1; off < 256; off <<= 1) {
        int u = (tid >= off) ? cntb[tid - off] : 0;
        __syncthreads();
        cntb[tid] += u;
        __syncthreads();
    }
    if (tid == bkt) dense_base = cntb[tid] - c;        // exclusive prefix
    if (bkt == 0 && tid == 255) offs[NN] = cntb[255];  // == NE
    __syncthreads();

    const int n = gcursor[bkt] - bkt * CAP;
    const int2* P = pairs + (size_t)bkt * CAP;

    cnt512[tid] = 0; cnt512[tid + 256] = 0;
    __syncthreads();
    for (int i = tid; i < n; i += 256)
        atomicAdd(&cnt512[P[i].y & 511], 1);
    __syncthreads();

    int c0 = cnt512[2 * tid], c1 = cnt512[2 * tid + 1];
    int ps = c0 + c1;
    cntb[tid] = ps;
    __syncthreads();
    for (int off = 1; off < 256; off <<= 1) {
        int u = (tid >= off) ? cntb[tid - off] : 0;
        __syncthreads();
        cntb[tid] += u;
        __syncthreads();
    }
    int ex = cntb[tid] - ps;
    pref[2 * tid] = ex;
    pref[2 * tid + 1] = ex + c0;

    {
        int d0 = bkt * 512 + 2 * tid;
        if (d0 < NN)     offs[d0]     = dense_base + ex;
        if (d0 + 1 < NN) offs[d0 + 1] = dense_base + ex + c0;
    }
    __syncthreads();

    for (int i = tid; i < n; i += 256) {
        int2 p = P[i];
        int pos = atomicAdd(&pref[p.y & 511], 1);
        srcs[dense_base + pos] = p.x;
    }
}

// ---- gather-reduce: one node per QUARTER-wave (r16 winner, unroll-2) ----
__global__ __launch_bounds__(256) void gather_kernel(
    const uint4* __restrict__ xtu4,        // xt rows: [NN][16] uint4 (8 bf16)
    const int* __restrict__ offs, const int* __restrict__ srcs,
    float* __restrict__ out)
{
    const int gid  = blockIdx.x * 256 + threadIdx.x;
    const int lane = threadIdx.x & 63;
    const int q    = lane >> 4;            // quarter 0..3
    const int l16  = lane & 15;
    const int node = ((gid >> 6) << 2) + q;
    const int nd   = node < NN ? node : NN - 1;

    uint4 own = xtu4[(size_t)nd * 16 + l16];        // residual
    float a0 = bflo(own.x), a1 = bfhi(own.x);
    float a2 = bflo(own.y), a3 = bfhi(own.y);
    float a4 = bflo(own.z), a5 = bfhi(own.z);
    float a6 = bflo(own.w), a7 = bfhi(own.w);

    int beg = offs[nd];
    const int end = offs[nd + 1];

    while (beg < end) {
        const int n = min(end - beg, 16);
        const int myidx = (l16 < n) ? srcs[beg + l16] : 0;
        int k = 0;
        for (; k + 1 < n; k += 2) {                 // 2 loads in flight
            int s0 = __shfl(myidx, (q << 4) + k);
            int s1 = __shfl(myidx, (q << 4) + k + 1);
            uint4 h0 = xtu4[(size_t)s0 * 16 + l16];
            uint4 h1 = xtu4[(size_t)s1 * 16 + l16];
            a0 += bflo(h0.x); a1 += bfhi(h0.x);
            a2 += bflo(h0.y); a3 += bfhi(h0.y);
            a4 += bflo(h0.z); a5 += bfhi(h0.z);
            a6 += bflo(h0.w); a7 += bfhi(h0.w);
            a0 += bflo(h1.x); a1 += bfhi(h1.x);
            a2 += bflo(h1.y); a3 += bfhi(h1.y);
            a4 += bflo(h1.z); a5 += bfhi(h1.z);
            a6 += bflo(h1.w); a7 += bfhi(h1.w);
        }
        if (k < n) {
            int s0 = __shfl(myidx, (q << 4) + k);
            uint4 h0 = xtu4[(size_t)s0 * 16 + l16];
            a0 += bflo(h0.x); a1 += bfhi(h0.x);
            a2 += bflo(h0.y); a3 += bfhi(h0.y);
            a4 += bflo(h0.z); a5 += bfhi(h0.z);
            a6 += bflo(h0.w); a7 += bfhi(h0.w);
        }
        beg += n;
    }

    if (node < NN) {
        float4* o4 = reinterpret_cast<float4*>(out) + (size_t)node * 32 + l16 * 2;
        o4[0] = make_float4(a0, a1, a2, a3);
        o4[1] = make_float4(a4, a5, a6, a7);
    }
}

extern "C" void kernel_launch(void* const* d_in, const int* in_sizes, int n_in,
                              void* d_out, int out_size, void* d_ws, size_t ws_size,
                              hipStream_t stream) {
    const float* x  = (const float*)d_in[0];
    const int*   ei = (const int*)d_in[1];   // [2][NE] int32
    const float* W  = (const float*)d_in[2];
    const float* b  = (const float*)d_in[3];
    float* out = (float*)d_out;

    __bf16* xt     = (__bf16*)d_ws;                       // 25.6 MB
    int2*   pairs  = (int2*)(xt + (size_t)NN * CH);       // 256*CAP*8B = 8 MB
    int*    srcs   = (int*)(pairs + (size_t)256 * CAP);   // NE = 2.5 MB
    int*    offs   = srcs + NE;                           // NN+1
    int*    gcur   = offs + NN + 1;                       // 256
    __bf16* Wb     = (__bf16*)(gcur + 256);               // 32 KB

    prep_kernel<<<1 + WCONV_BLOCKS, 256, 0, stream>>>(gcur, W, Wb);
    gemm_bucket_kernel<<<BUCKET_BLOCKS + GEMM_BLOCKS, 512, 0, stream>>>(
        x, Wb, b, xt, ei, gcur, pairs);
    place2_kernel<<<NB, 256, 0, stream>>>(gcur, pairs, srcs, offs);
    const int gwaves = (NN + 3) / 4;   // 4 nodes per wave
    gather_kernel<<<(gwaves * 64 + 255) / 256, 256, 0, stream>>>(
        (const uint4*)xt, offs, srcs, out);
}

// Round 24
// 82.000 us; speedup vs baseline: 1.0434x; 1.0434x over previous
//
#include <hip/hip_runtime.h>

constexpr int NN = 100000;
constexpr int CH = 128;
constexpr int NE = 625000;
constexpr int GEMM_BLOCKS = (NN + 127) / 128;      // 782 (128 rows/block, 8 waves)
constexpr int BUCKET_BLOCKS = 256;
constexpr int EDGES_PER_BLOCK = (NE + BUCKET_BLOCKS - 1) / BUCKET_BLOCKS;  // 2442
constexpr int NB = 196;                            // ceil(NN/512) coarse buckets
constexpr int CAP = 4096;                          // slots/bucket (max ~3390)
constexpr int WCONV_BLOCKS = 16;                   // 16384 elems / 1024

typedef __bf16 bf16x8 __attribute__((ext_vector_type(8)));
typedef __bf16 bf16x4 __attribute__((ext_vector_type(4)));
typedef float  f32x4  __attribute__((ext_vector_type(4)));

__device__ __forceinline__ float bflo(uint u) { return __uint_as_float(u << 16); }
__device__ __forceinline__ float bfhi(uint u) { return __uint_as_float(u & 0xffff0000u); }

// Async 16B global->LDS DMA. LDS dest is wave-uniform base + lane*16.
__device__ __forceinline__ void async_copy16(const void* g, void* l) {
    __builtin_amdgcn_global_load_lds(
        (const __attribute__((address_space(1))) unsigned int*)(uintptr_t)g,
        (__attribute__((address_space(3))) unsigned int*)(uintptr_t)l,
        16, 0, 0);
}

// ---- prep: init bucket cursors + convert W to bf16 swizzled ----
__global__ __launch_bounds__(256) void prep_kernel(
    int* __restrict__ gcursor, const float* __restrict__ W, __bf16* __restrict__ Wb)
{
    if (blockIdx.x == 0) {
        gcursor[threadIdx.x] = threadIdx.x * CAP;
        return;
    }
    int i = (blockIdx.x - 1) * 256 + threadIdx.x;   // float4 group, 4096 total
    int ch = i >> 5;
    int k0 = (i & 31) * 4;
    float4 v = reinterpret_cast<const float4*>(W)[i];
    bf16x4 h = {(__bf16)v.x, (__bf16)v.y, (__bf16)v.z, (__bf16)v.w};
    *reinterpret_cast<bf16x4*>(&Wb[ch * 128 + (k0 ^ ((ch & 7) << 3))]) = h;
}

// ---- fused: coarse bucketing (blocks < BUCKET_BLOCKS) + MFMA GEMM ----
// 512 threads/block. GEMM: 8 waves share one 32KB W stage (128 rows/block);
// 4 blocks/CU x 8 waves = full wave slots. Bucket: per-edge atomics are
// LDS-only; global atomics are <=50K range reservations.
__global__ __launch_bounds__(512) void gemm_bucket_kernel(
    const float* __restrict__ x, const __bf16* __restrict__ Wb,
    const float* __restrict__ b, __bf16* __restrict__ xt,
    const int* __restrict__ ei, int* __restrict__ gcursor, int2* __restrict__ pairs)
{
    __shared__ __bf16 wlds[128 * 128];     // 32 KB; bucket blocks alias it
    const int tid = threadIdx.x;

    if (blockIdx.x < BUCKET_BLOCKS) {
        int* lhist = (int*)wlds;           // [256]
        int* lbase = lhist + 256;          // [256]
        const int e0 = blockIdx.x * EDGES_PER_BLOCK;
        const int myN = min(NE - e0, EDGES_PER_BLOCK);
        if (tid < 256) lhist[tid] = 0;
        __syncthreads();
        for (int i = tid; i < myN; i += 512) {
            int dst = ei[NE + e0 + i];
            atomicAdd(&lhist[dst >> 9], 1);
        }
        __syncthreads();
        if (tid < 256) {
            int c = lhist[tid];
            if (c) lbase[tid] = atomicAdd(&gcursor[tid], c);
            lhist[tid] = 0;
        }
        __syncthreads();
        for (int i = tid; i < myN; i += 512) {
            int src = ei[e0 + i];
            int dst = ei[NE + e0 + i];
            int bin = dst >> 9;
            int r = atomicAdd(&lhist[bin], 1);
            pairs[lbase[bin] + r] = make_int2(src, dst);
        }
        return;
    }

    const int lane = tid & 63;
    const int w    = tid >> 6;             // wave id 0..7
    const int lm = lane & 15;              // x row (n) / W channel (m) in tile
    const int lk = lane >> 4;              // k-group / channel-quad selector
    const int row = (blockIdx.x - BUCKET_BLOCKS) * 128 + w * 16 + lm;
    const int rc  = row < NN ? row : NN - 1;

    // x fragment loads first (HBM, longest latency): 8 independent dwordx4.
    const float* xrow = x + (size_t)rc * CH;
    float4 xr[8];
    #pragma unroll
    for (int ks = 0; ks < 4; ++ks) {
        const float4* p = reinterpret_cast<const float4*>(xrow + ks * 32 + lk * 8);
        xr[ks * 2]     = p[0];
        xr[ks * 2 + 1] = p[1];
    }

    // Async W staging: 2048 granules of 16B over 512 threads = 4 issues.
    const bf16x8* Wb8 = reinterpret_cast<const bf16x8*>(Wb);
    #pragma unroll
    for (int it = 0; it < 4; ++it) {
        async_copy16(Wb8 + it * 512 + tid,
                     (char*)wlds + (size_t)(it * 512 + w * 64) * 16);
    }

    // Convert x to bf16 fragments while DMAs fly.
    bf16x8 bfrag[4];
    #pragma unroll
    for (int ks = 0; ks < 4; ++ks) {
        float4 u = xr[ks * 2], v = xr[ks * 2 + 1];
        bfrag[ks][0] = (__bf16)u.x; bfrag[ks][1] = (__bf16)u.y;
        bfrag[ks][2] = (__bf16)u.z; bfrag[ks][3] = (__bf16)u.w;
        bfrag[ks][4] = (__bf16)v.x; bfrag[ks][5] = (__bf16)v.y;
        bfrag[ks][6] = (__bf16)v.z; bfrag[ks][7] = (__bf16)v.w;
    }

    __syncthreads();   // drains vmcnt (x loads + LDS DMAs)

    const float4* B4 = reinterpret_cast<const float4*>(b);
    const int swz = (lm & 7) << 3;

    #pragma unroll
    for (int t = 0; t < 8; ++t) {
        const int ch = t * 16 + lm;
        float4 bv = B4[t * 4 + lk];
        f32x4 acc = {bv.x, bv.y, bv.z, bv.w};
        #pragma unroll
        for (int ks = 0; ks < 4; ++ks) {
            bf16x8 afrag = *reinterpret_cast<const bf16x8*>(
                &wlds[ch * 128 + ((ks * 32 + lk * 8) ^ swz)]);
            acc = __builtin_amdgcn_mfma_f32_16x16x32_bf16(afrag, bfrag[ks], acc, 0, 0, 0);
        }
        if (row < NN) {
            const int c0 = t * 16 + lk * 4;
            bf16x4 hv = {(__bf16)acc[0], (__bf16)acc[1], (__bf16)acc[2], (__bf16)acc[3]};
            *reinterpret_cast<bf16x4*>(&xt[(size_t)row * CH + c0]) = hv;
        }
    }
}

// ---- phase 2: per-bucket LDS counting sort -> dense srcs + offs ----
__global__ __launch_bounds__(256) void place2_kernel(
    const int* __restrict__ gcursor, const int2* __restrict__ pairs,
    int* __restrict__ srcs, int* __restrict__ offs)
{
    __shared__ int cntb[256];      // bucket counts -> scan -> dense bases
    __shared__ int cnt512[512];
    __shared__ int pref[512];      // prefix, then reused as cursor
    __shared__ int dense_base;
    const int tid = threadIdx.x;
    const int bkt = blockIdx.x;

    int c = gcursor[tid] - tid * CAP;     // 0 for unused bins
    cntb[tid] = c;
    __syncthreads();
    for (int off = 1; off < 256; off <<= 1) {
        int u = (tid >= off) ? cntb[tid - off] : 0;
        __syncthreads();
        cntb[tid] += u;
        __syncthreads();
    }
    if (tid == bkt) dense_base = cntb[tid] - c;        // exclusive prefix
    if (bkt == 0 && tid == 255) offs[NN] = cntb[255];  // == NE
    __syncthreads();

    const int n = gcursor[bkt] - bkt * CAP;
    const int2* P = pairs + (size_t)bkt * CAP;

    cnt512[tid] = 0; cnt512[tid + 256] = 0;
    __syncthreads();
    for (int i = tid; i < n; i += 256)
        atomicAdd(&cnt512[P[i].y & 511], 1);
    __syncthreads();

    int c0 = cnt512[2 * tid], c1 = cnt512[2 * tid + 1];
    int ps = c0 + c1;
    cntb[tid] = ps;
    __syncthreads();
    for (int off = 1; off < 256; off <<= 1) {
        int u = (tid >= off) ? cntb[tid - off] : 0;
        __syncthreads();
        cntb[tid] += u;
        __syncthreads();
    }
    int ex = cntb[tid] - ps;
    pref[2 * tid] = ex;
    pref[2 * tid + 1] = ex + c0;

    {
        int d0 = bkt * 512 + 2 * tid;
        if (d0 < NN)     offs[d0]     = dense_base + ex;
        if (d0 + 1 < NN) offs[d0 + 1] = dense_base + ex + c0;
    }
    __syncthreads();

    for (int i = tid; i < n; i += 256) {
        int2 p = P[i];
        int pos = atomicAdd(&pref[p.y & 511], 1);
        srcs[dense_base + pos] = p.x;
    }
}

// ---- gather-reduce: one node per QUARTER-wave (4 nodes/wave) ----
__global__ __launch_bounds__(256) void gather_kernel(
    const uint4* __restrict__ xtu4,        // xt rows: [NN][16] uint4 (8 bf16)
    const int* __restrict__ offs, const int* __restrict__ srcs,
    float* __restrict__ out)
{
    const int gid  = blockIdx.x * 256 + threadIdx.x;
    const int lane = threadIdx.x & 63;
    const int q    = lane >> 4;            // quarter 0..3
    const int l16  = lane & 15;
    const int node = ((gid >> 6) << 2) + q;
    const int nd   = node < NN ? node : NN - 1;

    uint4 own = xtu4[(size_t)nd * 16 + l16];        // residual
    float a0 = bflo(own.x), a1 = bfhi(own.x);
    float a2 = bflo(own.y), a3 = bfhi(own.y);
    float a4 = bflo(own.z), a5 = bfhi(own.z);
    float a6 = bflo(own.w), a7 = bfhi(own.w);

    int beg = offs[nd];
    const int end = offs[nd + 1];

    while (beg < end) {
        const int n = min(end - beg, 16);
        const int myidx = (l16 < n) ? srcs[beg + l16] : 0;
        int k = 0;
        for (; k + 1 < n; k += 2) {                 // 2 loads in flight
            int s0 = __shfl(myidx, (q << 4) + k);
            int s1 = __shfl(myidx, (q << 4) + k + 1);
            uint4 h0 = xtu4[(size_t)s0 * 16 + l16];
            uint4 h1 = xtu4[(size_t)s1 * 16 + l16];
            a0 += bflo(h0.x); a1 += bfhi(h0.x);
            a2 += bflo(h0.y); a3 += bfhi(h0.y);
            a4 += bflo(h0.z); a5 += bfhi(h0.z);
            a6 += bflo(h0.w); a7 += bfhi(h0.w);
            a0 += bflo(h1.x); a1 += bfhi(h1.x);
            a2 += bflo(h1.y); a3 += bfhi(h1.y);
            a4 += bflo(h1.z); a5 += bfhi(h1.z);
            a6 += bflo(h1.w); a7 += bfhi(h1.w);
        }
        if (k < n) {
            int s0 = __shfl(myidx, (q << 4) + k);
            uint4 h0 = xtu4[(size_t)s0 * 16 + l16];
            a0 += bflo(h0.x); a1 += bfhi(h0.x);
            a2 += bflo(h0.y); a3 += bfhi(h0.y);
            a4 += bflo(h0.z); a5 += bfhi(h0.z);
            a6 += bflo(h0.w); a7 += bfhi(h0.w);
        }
        beg += n;
    }

    if (node < NN) {
        float4* o4 = reinterpret_cast<float4*>(out) + (size_t)node * 32 + l16 * 2;
        o4[0] = make_float4(a0, a1, a2, a3);
        o4[1] = make_float4(a4, a5, a6, a7);
    }
}

extern "C" void kernel_launch(void* const* d_in, const int* in_sizes, int n_in,
                              void* d_out, int out_size, void* d_ws, size_t ws_size,
                              hipStream_t stream) {
    const float* x  = (const float*)d_in[0];
    const int*   ei = (const int*)d_in[1];   // [2][NE] int32
    const float* W  = (const float*)d_in[2];
    const float* b  = (const float*)d_in[3];
    float* out = (float*)d_out;

    __bf16* xt     = (__bf16*)d_ws;                       // 25.6 MB
    int2*   pairs  = (int2*)(xt + (size_t)NN * CH);       // 256*CAP*8B = 8 MB
    int*    srcs   = (int*)(pairs + (size_t)256 * CAP);   // NE = 2.5 MB
    int*    offs   = srcs + NE;                           // NN+1
    int*    gcur   = offs + NN + 1;                       // 256
    __bf16* Wb     = (__bf16*)(gcur + 256);               // 32 KB

    prep_kernel<<<1 + WCONV_BLOCKS, 256, 0, stream>>>(gcur, W, Wb);
    gemm_bucket_kernel<<<BUCKET_BLOCKS + GEMM_BLOCKS, 512, 0, stream>>>(
        x, Wb, b, xt, ei, gcur, pairs);
    place2_kernel<<<NB, 256, 0, stream>>>(gcur, pairs, srcs, offs);
    const int gwaves = (NN + 3) / 4;   // 4 nodes per wave
    gather_kernel<<<(gwaves * 64 + 255) / 256, 256, 0, stream>>>(
        (const uint4*)xt, offs, srcs, out);
}

// Round 25
// 81.703 us; speedup vs baseline: 1.0472x; 1.0036x over previous
//
#include <hip/hip_runtime.h>

constexpr int NN = 100000;
constexpr int CH = 128;
constexpr int NE = 625000;
constexpr int GEMM_BLOCKS = (NN + 127) / 128;      // 782 (128 rows/block, 8 waves)
constexpr int BUCKET_BLOCKS = 256;
constexpr int EDGES_PER_BLOCK = (NE + BUCKET_BLOCKS - 1) / BUCKET_BLOCKS;  // 2442
constexpr int NB = 196;                            // ceil(NN/512) coarse buckets
constexpr int CAP = 4096;                          // slots/bucket (max ~3390)
constexpr int WCONV_BLOCKS = 16;                   // 16384 elems / 1024

typedef __bf16 bf16x8 __attribute__((ext_vector_type(8)));
typedef __bf16 bf16x4 __attribute__((ext_vector_type(4)));
typedef float  f32x4  __attribute__((ext_vector_type(4)));

__device__ __forceinline__ float bflo(uint u) { return __uint_as_float(u << 16); }
__device__ __forceinline__ float bfhi(uint u) { return __uint_as_float(u & 0xffff0000u); }

// Async 16B global->LDS DMA. LDS dest is wave-uniform base + lane*16.
__device__ __forceinline__ void async_copy16(const void* g, void* l) {
    __builtin_amdgcn_global_load_lds(
        (const __attribute__((address_space(1))) unsigned int*)(uintptr_t)g,
        (__attribute__((address_space(3))) unsigned int*)(uintptr_t)l,
        16, 0, 0);
}

// ---- prep: init bucket cursors + convert W to bf16 swizzled ----
__global__ __launch_bounds__(256) void prep_kernel(
    int* __restrict__ gcursor, const float* __restrict__ W, __bf16* __restrict__ Wb)
{
    if (blockIdx.x == 0) {
        gcursor[threadIdx.x] = threadIdx.x * CAP;
        return;
    }
    int i = (blockIdx.x - 1) * 256 + threadIdx.x;   // float4 group, 4096 total
    int ch = i >> 5;
    int k0 = (i & 31) * 4;
    float4 v = reinterpret_cast<const float4*>(W)[i];
    bf16x4 h = {(__bf16)v.x, (__bf16)v.y, (__bf16)v.z, (__bf16)v.w};
    *reinterpret_cast<bf16x4*>(&Wb[ch * 128 + (k0 ^ ((ch & 7) << 3))]) = h;
}

// ---- fused: coarse bucketing (blocks < BUCKET_BLOCKS) + MFMA GEMM ----
__global__ __launch_bounds__(512) void gemm_bucket_kernel(
    const float* __restrict__ x, const __bf16* __restrict__ Wb,
    const float* __restrict__ b, __bf16* __restrict__ xt,
    const int* __restrict__ ei, int* __restrict__ gcursor, int2* __restrict__ pairs)
{
    __shared__ __bf16 wlds[128 * 128];     // 32 KB; bucket blocks alias it
    const int tid = threadIdx.x;

    if (blockIdx.x < BUCKET_BLOCKS) {
        int* lhist = (int*)wlds;           // [256]
        int* lbase = lhist + 256;          // [256]
        const int e0 = blockIdx.x * EDGES_PER_BLOCK;
        const int myN = min(NE - e0, EDGES_PER_BLOCK);
        if (tid < 256) lhist[tid] = 0;
        __syncthreads();
        for (int i = tid; i < myN; i += 512) {
            int dst = ei[NE + e0 + i];
            atomicAdd(&lhist[dst >> 9], 1);
        }
        __syncthreads();
        if (tid < 256) {
            int c = lhist[tid];
            if (c) lbase[tid] = atomicAdd(&gcursor[tid], c);
            lhist[tid] = 0;
        }
        __syncthreads();
        for (int i = tid; i < myN; i += 512) {
            int src = ei[e0 + i];
            int dst = ei[NE + e0 + i];
            int bin = dst >> 9;
            int r = atomicAdd(&lhist[bin], 1);
            pairs[lbase[bin] + r] = make_int2(src, dst);
        }
        return;
    }

    const int lane = tid & 63;
    const int w    = tid >> 6;             // wave id 0..7
    const int lm = lane & 15;              // x row (n) / W channel (m) in tile
    const int lk = lane >> 4;              // k-group / channel-quad selector
    const int row = (blockIdx.x - BUCKET_BLOCKS) * 128 + w * 16 + lm;
    const int rc  = row < NN ? row : NN - 1;

    // x fragment loads first (HBM, longest latency): 8 independent dwordx4.
    const float* xrow = x + (size_t)rc * CH;
    float4 xr[8];
    #pragma unroll
    for (int ks = 0; ks < 4; ++ks) {
        const float4* p = reinterpret_cast<const float4*>(xrow + ks * 32 + lk * 8);
        xr[ks * 2]     = p[0];
        xr[ks * 2 + 1] = p[1];
    }

    // Async W staging: 2048 granules of 16B over 512 threads = 4 issues.
    const bf16x8* Wb8 = reinterpret_cast<const bf16x8*>(Wb);
    #pragma unroll
    for (int it = 0; it < 4; ++it) {
        async_copy16(Wb8 + it * 512 + tid,
                     (char*)wlds + (size_t)(it * 512 + w * 64) * 16);
    }

    // Convert x to bf16 fragments while DMAs fly.
    bf16x8 bfrag[4];
    #pragma unroll
    for (int ks = 0; ks < 4; ++ks) {
        float4 u = xr[ks * 2], v = xr[ks * 2 + 1];
        bfrag[ks][0] = (__bf16)u.x; bfrag[ks][1] = (__bf16)u.y;
        bfrag[ks][2] = (__bf16)u.z; bfrag[ks][3] = (__bf16)u.w;
        bfrag[ks][4] = (__bf16)v.x; bfrag[ks][5] = (__bf16)v.y;
        bfrag[ks][6] = (__bf16)v.z; bfrag[ks][7] = (__bf16)v.w;
    }

    __syncthreads();   // drains vmcnt (x loads + LDS DMAs)

    const float4* B4 = reinterpret_cast<const float4*>(b);
    const int swz = (lm & 7) << 3;

    #pragma unroll
    for (int t = 0; t < 8; ++t) {
        const int ch = t * 16 + lm;
        float4 bv = B4[t * 4 + lk];
        f32x4 acc = {bv.x, bv.y, bv.z, bv.w};
        #pragma unroll
        for (int ks = 0; ks < 4; ++ks) {
            bf16x8 afrag = *reinterpret_cast<const bf16x8*>(
                &wlds[ch * 128 + ((ks * 32 + lk * 8) ^ swz)]);
            acc = __builtin_amdgcn_mfma_f32_16x16x32_bf16(afrag, bfrag[ks], acc, 0, 0, 0);
        }
        if (row < NN) {
            const int c0 = t * 16 + lk * 4;
            bf16x4 hv = {(__bf16)acc[0], (__bf16)acc[1], (__bf16)acc[2], (__bf16)acc[3]};
            *reinterpret_cast<bf16x4*>(&xt[(size_t)row * CH + c0]) = hv;
        }
    }
}

// ---- phase 2: per-bucket LDS counting sort -> dense srcs + offs ----
__global__ __launch_bounds__(256) void place2_kernel(
    const int* __restrict__ gcursor, const int2* __restrict__ pairs,
    int* __restrict__ srcs, int* __restrict__ offs)
{
    __shared__ int cntb[256];
    __shared__ int cnt512[512];
    __shared__ int pref[512];
    __shared__ int dense_base;
    const int tid = threadIdx.x;
    const int bkt = blockIdx.x;

    int c = gcursor[tid] - tid * CAP;     // 0 for unused bins
    cntb[tid] = c;
    __syncthreads();
    for (int off = 1; off < 256; off <<= 1) {
        int u = (tid >= off) ? cntb[tid - off] : 0;
        __syncthreads();
        cntb[tid] += u;
        __syncthreads();
    }
    if (tid == bkt) dense_base = cntb[tid] - c;        // exclusive prefix
    if (bkt == 0 && tid == 255) offs[NN] = cntb[255];  // == NE
    __syncthreads();

    const int n = gcursor[bkt] - bkt * CAP;
    const int2* P = pairs + (size_t)bkt * CAP;

    cnt512[tid] = 0; cnt512[tid + 256] = 0;
    __syncthreads();
    for (int i = tid; i < n; i += 256)
        atomicAdd(&cnt512[P[i].y & 511], 1);
    __syncthreads();

    int c0 = cnt512[2 * tid], c1 = cnt512[2 * tid + 1];
    int ps = c0 + c1;
    cntb[tid] = ps;
    __syncthreads();
    for (int off = 1; off < 256; off <<= 1) {
        int u = (tid >= off) ? cntb[tid - off] : 0;
        __syncthreads();
        cntb[tid] += u;
        __syncthreads();
    }
    int ex = cntb[tid] - ps;
    pref[2 * tid] = ex;
    pref[2 * tid + 1] = ex + c0;

    {
        int d0 = bkt * 512 + 2 * tid;
        if (d0 < NN)     offs[d0]     = dense_base + ex;
        if (d0 + 1 < NN) offs[d0 + 1] = dense_base + ex + c0;
    }
    __syncthreads();

    for (int i = tid; i < n; i += 256) {
        int2 p = P[i];
        int pos = atomicAdd(&pref[p.y & 511], 1);
        srcs[dense_base + pos] = p.x;
    }
}

// ---- gather-reduce: TWO nodes per quarter-wave (8 nodes/wave) ----
// Each quarter walks two independent segments in lockstep: up to 4 loads
// in flight per iteration (2x MLP vs one-node). Invalid slots clamp to
// row 0 (L2-hot, ~free); accumulates predicated (uniform per quarter).
__global__ __launch_bounds__(256) void gather_kernel(
    const uint4* __restrict__ xtu4,        // xt rows: [NN][16] uint4 (8 bf16)
    const int* __restrict__ offs, const int* __restrict__ srcs,
    float* __restrict__ out)
{
    const int gid  = blockIdx.x * 256 + threadIdx.x;
    const int lane = threadIdx.x & 63;
    const int q    = lane >> 4;            // quarter 0..3
    const int l16  = lane & 15;
    const int qb   = q << 4;
    const int base = (gid >> 6) * 8;
    const int nodeA = base + q;
    const int nodeB = base + 4 + q;
    const int ndA = nodeA < NN ? nodeA : NN - 1;
    const int ndB = nodeB < NN ? nodeB : NN - 1;

    uint4 ownA = xtu4[(size_t)ndA * 16 + l16];      // residuals
    uint4 ownB = xtu4[(size_t)ndB * 16 + l16];
    float A0 = bflo(ownA.x), A1 = bfhi(ownA.x), A2 = bflo(ownA.y), A3 = bfhi(ownA.y);
    float A4 = bflo(ownA.z), A5 = bfhi(ownA.z), A6 = bflo(ownA.w), A7 = bfhi(ownA.w);
    float B0 = bflo(ownB.x), B1 = bfhi(ownB.x), B2 = bflo(ownB.y), B3 = bfhi(ownB.y);
    float B4 = bflo(ownB.z), B5 = bfhi(ownB.z), B6 = bflo(ownB.w), B7 = bfhi(ownB.w);

    int begA = offs[ndA];
    const int endA = offs[ndA + 1];
    int begB = offs[ndB];
    const int endB = offs[ndB + 1];

    while (begA < endA || begB < endB) {
        const int nA = max(min(endA - begA, 16), 0);
        const int nB = max(min(endB - begB, 16), 0);
        const int idxA = (l16 < nA) ? srcs[begA + l16] : 0;
        const int idxB = (l16 < nB) ? srcs[begB + l16] : 0;
        const int kmax = max(nA, nB);

        for (int k = 0; k < kmax; k += 2) {
            const bool a0 = k < nA, a1 = k + 1 < nA;
            const bool b0 = k < nB, b1 = k + 1 < nB;
            // invalid -> row 0 (all 16 lanes same 256B line, L2-hot)
            int sA0 = a0 ? __shfl(idxA, qb + k)     : 0;
            int sA1 = a1 ? __shfl(idxA, qb + k + 1) : 0;
            int sB0 = b0 ? __shfl(idxB, qb + k)     : 0;
            int sB1 = b1 ? __shfl(idxB, qb + k + 1) : 0;
            uint4 hA0 = xtu4[(size_t)sA0 * 16 + l16];
            uint4 hA1 = xtu4[(size_t)sA1 * 16 + l16];
            uint4 hB0 = xtu4[(size_t)sB0 * 16 + l16];
            uint4 hB1 = xtu4[(size_t)sB1 * 16 + l16];
            if (a0) {
                A0 += bflo(hA0.x); A1 += bfhi(hA0.x); A2 += bflo(hA0.y); A3 += bfhi(hA0.y);
                A4 += bflo(hA0.z); A5 += bfhi(hA0.z); A6 += bflo(hA0.w); A7 += bfhi(hA0.w);
            }
            if (a1) {
                A0 += bflo(hA1.x); A1 += bfhi(hA1.x); A2 += bflo(hA1.y); A3 += bfhi(hA1.y);
                A4 += bflo(hA1.z); A5 += bfhi(hA1.z); A6 += bflo(hA1.w); A7 += bfhi(hA1.w);
            }
            if (b0) {
                B0 += bflo(hB0.x); B1 += bfhi(hB0.x); B2 += bflo(hB0.y); B3 += bfhi(hB0.y);
                B4 += bflo(hB0.z); B5 += bfhi(hB0.z); B6 += bflo(hB0.w); B7 += bfhi(hB0.w);
            }
            if (b1) {
                B0 += bflo(hB1.x); B1 += bfhi(hB1.x); B2 += bflo(hB1.y); B3 += bfhi(hB1.y);
                B4 += bflo(hB1.z); B5 += bfhi(hB1.z); B6 += bflo(hB1.w); B7 += bfhi(hB1.w);
            }
        }
        begA += nA;
        begB += nB;
    }

    if (nodeA < NN) {
        float4* o4 = reinterpret_cast<float4*>(out) + (size_t)nodeA * 32 + l16 * 2;
        o4[0] = make_float4(A0, A1, A2, A3);
        o4[1] = make_float4(A4, A5, A6, A7);
    }
    if (nodeB < NN) {
        float4* o4 = reinterpret_cast<float4*>(out) + (size_t)nodeB * 32 + l16 * 2;
        o4[0] = make_float4(B0, B1, B2, B3);
        o4[1] = make_float4(B4, B5, B6, B7);
    }
}

extern "C" void kernel_launch(void* const* d_in, const int* in_sizes, int n_in,
                              void* d_out, int out_size, void* d_ws, size_t ws_size,
                              hipStream_t stream) {
    const float* x  = (const float*)d_in[0];
    const int*   ei = (const int*)d_in[1];   // [2][NE] int32
    const float* W  = (const float*)d_in[2];
    const float* b  = (const float*)d_in[3];
    float* out = (float*)d_out;

    __bf16* xt     = (__bf16*)d_ws;                       // 25.6 MB
    int2*   pairs  = (int2*)(xt + (size_t)NN * CH);       // 256*CAP*8B = 8 MB
    int*    srcs   = (int*)(pairs + (size_t)256 * CAP);   // NE = 2.5 MB
    int*    offs   = srcs + NE;                           // NN+1
    int*    gcur   = offs + NN + 1;                       // 256
    __bf16* Wb     = (__bf16*)(gcur + 256);               // 32 KB

    prep_kernel<<<1 + WCONV_BLOCKS, 256, 0, stream>>>(gcur, W, Wb);
    gemm_bucket_kernel<<<BUCKET_BLOCKS + GEMM_BLOCKS, 512, 0, stream>>>(
        x, Wb, b, xt, ei, gcur, pairs);
    place2_kernel<<<NB, 256, 0, stream>>>(gcur, pairs, srcs, offs);
    const int gwaves = (NN + 7) / 8;   // 8 nodes per wave
    gather_kernel<<<(gwaves * 64 + 255) / 256, 256, 0, stream>>>(
        (const uint4*)xt, offs, srcs, out);
}